// Round 1
// baseline (221.705 us; speedup 1.0000x reference)
//
#include <hip/hip_runtime.h>
#include <hip/hip_bf16.h>

// Problem constants
#define B_ 32
#define L_ 512
#define I_ 1024
#define O_ 1024

// Tile config
#define BM 128
#define BN 128
#define BK 32
#define LDSPAD 40  // LDS row stride in bf16 elems (32 + 8 pad -> 80B rows, 16B aligned)

typedef float f32x4 __attribute__((ext_vector_type(4)));
typedef __bf16 bf16x8 __attribute__((ext_vector_type(8)));

__global__ void bayes_gemm_kernel(const float* __restrict__ x,
                                  const float* __restrict__ wmean,
                                  const float* __restrict__ wlogvar,
                                  const float* __restrict__ bias,
                                  const float* __restrict__ noise,
                                  float* __restrict__ out)
{
    __shared__ __bf16 As[BM * LDSPAD];
    __shared__ __bf16 Bs[BN * LDSPAD];

    // batch-major block ordering: blocks of one batch are contiguous
    const int bid  = blockIdx.x;
    const int b    = bid >> 5;        // 32 blocks per batch
    const int rem  = bid & 31;
    const int mt   = rem >> 3;        // 4 M-tiles (L/128)
    const int nt   = rem & 7;         // 8 N-tiles (O/128)
    const int brow = mt * BM;
    const int bcol = nt * BN;

    const int t    = threadIdx.x;     // 0..255
    const int wave = t >> 6;
    const int lane = t & 63;
    const int wr   = wave >> 1;       // 2x2 wave grid, each wave owns 64x64
    const int wc   = wave & 1;

    const int hr = lane & 15;         // row/col within 16x16 fragment
    const int kq = lane >> 4;         // k-quarter: k offset = kq*8 (input), row base = kq*4 (output)

    const float* xb = x     + (size_t)b * L_ * I_;
    const float* nb = noise + (size_t)b * O_ * I_;

    f32x4 acc[4][4];
    #pragma unroll
    for (int m = 0; m < 4; ++m)
        #pragma unroll
        for (int n = 0; n < 4; ++n)
            acc[m][n] = (f32x4)(0.0f);

    for (int k0 = 0; k0 < I_; k0 += BK) {
        // ---- stage A: x tile (128 x 32 f32 -> bf16) ----
        #pragma unroll
        for (int j = 0; j < 4; ++j) {
            const int s   = t + j * 256;     // float4 slot 0..1023
            const int row = s >> 3;          // 8 float4 per row
            const int q   = s & 7;
            const float4 v = *(const float4*)(xb + (size_t)(brow + row) * I_ + k0 + q * 4);
            __bf16* dst = &As[row * LDSPAD + q * 4];
            dst[0] = (__bf16)v.x; dst[1] = (__bf16)v.y;
            dst[2] = (__bf16)v.z; dst[3] = (__bf16)v.w;
        }
        // ---- stage B: sampled weight tile W = mean + noise * exp(0.5*logvar) ----
        #pragma unroll
        for (int j = 0; j < 4; ++j) {
            const int s   = t + j * 256;
            const int row = s >> 3;
            const int q   = s & 7;
            const size_t off = (size_t)(bcol + row) * I_ + k0 + q * 4;
            const float4 m4 = *(const float4*)(wmean   + off);
            const float4 l4 = *(const float4*)(wlogvar + off);
            const float4 n4 = *(const float4*)(nb      + off);
            const float w0 = m4.x + n4.x * __expf(0.5f * l4.x);
            const float w1 = m4.y + n4.y * __expf(0.5f * l4.y);
            const float w2 = m4.z + n4.z * __expf(0.5f * l4.z);
            const float w3 = m4.w + n4.w * __expf(0.5f * l4.w);
            __bf16* dst = &Bs[row * LDSPAD + q * 4];
            dst[0] = (__bf16)w0; dst[1] = (__bf16)w1;
            dst[2] = (__bf16)w2; dst[3] = (__bf16)w3;
        }
        __syncthreads();

        // ---- LDS -> frags -> MFMA ----
        bf16x8 af[4], bfr[4];
        #pragma unroll
        for (int m = 0; m < 4; ++m)
            af[m] = *(const bf16x8*)&As[(wr * 64 + m * 16 + hr) * LDSPAD + kq * 8];
        #pragma unroll
        for (int n = 0; n < 4; ++n)
            bfr[n] = *(const bf16x8*)&Bs[(wc * 64 + n * 16 + hr) * LDSPAD + kq * 8];
        #pragma unroll
        for (int m = 0; m < 4; ++m)
            #pragma unroll
            for (int n = 0; n < 4; ++n)
                acc[m][n] = __builtin_amdgcn_mfma_f32_16x16x32_bf16(af[m], bfr[n], acc[m][n], 0, 0, 0);

        __syncthreads();
    }

    // ---- epilogue: acc + bias -> out (f32) ----
    // C/D layout (verified, learn_hip m89): col = lane&15, row = (lane>>4)*4 + reg
    float* ob = out + (size_t)b * L_ * O_;
    #pragma unroll
    for (int n = 0; n < 4; ++n) {
        const int col = bcol + wc * 64 + n * 16 + hr;
        const float bv = bias[col];
        #pragma unroll
        for (int m = 0; m < 4; ++m) {
            const int row0 = brow + wr * 64 + m * 16 + kq * 4;
            #pragma unroll
            for (int j = 0; j < 4; ++j)
                ob[(size_t)(row0 + j) * O_ + col] = acc[m][n][j] + bv;
        }
    }
}

extern "C" void kernel_launch(void* const* d_in, const int* in_sizes, int n_in,
                              void* d_out, int out_size, void* d_ws, size_t ws_size,
                              hipStream_t stream) {
    const float* x       = (const float*)d_in[0];
    const float* wmean   = (const float*)d_in[1];
    const float* wlogvar = (const float*)d_in[2];
    const float* bias    = (const float*)d_in[3];
    const float* noise   = (const float*)d_in[4];
    float* out           = (float*)d_out;

    const int nblocks = B_ * (L_ / BM) * (O_ / BN);  // 32 * 4 * 8 = 1024
    bayes_gemm_kernel<<<dim3(nblocks), dim3(256), 0, stream>>>(
        x, wmean, wlogvar, bias, noise, out);
}

// Round 2
// 129.016 us; speedup vs baseline: 1.7184x; 1.7184x over previous
//
#include <hip/hip_runtime.h>
#include <hip/hip_bf16.h>
#include <stdint.h>

// Problem constants
#define B_ 32
#define L_ 512
#define I_ 1024
#define O_ 1024

typedef float  f32x4  __attribute__((ext_vector_type(4)));
typedef __bf16 bf16x4 __attribute__((ext_vector_type(4)));
typedef __bf16 bf16x8 __attribute__((ext_vector_type(8)));

// ---- async global->LDS, 16B per lane (global_load_lds_dwordx4) ----
// LDS dest is wave-uniform base + lane*16; our per-lane lds pointers are
// contiguous in lane order so either semantic reads identically.
__device__ __forceinline__ void gload_lds16(const void* g, void* l) {
    __builtin_amdgcn_global_load_lds(
        (const __attribute__((address_space(1))) uint32_t*)(uintptr_t)g,
        (__attribute__((address_space(3))) uint32_t*)(uint32_t)(uintptr_t)l,
        16, 0, 0);
}

// ============================ Pass 1a: W = mean + eps * exp(0.5*lv) ============================
__global__ void gen_w_kernel(const float* __restrict__ wmean,
                             const float* __restrict__ wlv,
                             const float* __restrict__ noise,
                             __bf16* __restrict__ W)
{
    const int n4 = B_ * O_ * I_ / 4;          // 8388608 float4 groups
    const int stride = gridDim.x * blockDim.x;
    for (int i = blockIdx.x * blockDim.x + threadIdx.x; i < n4; i += stride) {
        const int mi = i & (O_ * I_ / 4 - 1); // index into (O,I), reused per batch
        const f32x4 m4 = *(const f32x4*)(wmean + (size_t)mi * 4);
        const f32x4 l4 = *(const f32x4*)(wlv   + (size_t)mi * 4);
        const f32x4 e4 = *(const f32x4*)(noise + (size_t)i  * 4);
        bf16x4 w;
        w[0] = (__bf16)(m4[0] + e4[0] * __expf(0.5f * l4[0]));
        w[1] = (__bf16)(m4[1] + e4[1] * __expf(0.5f * l4[1]));
        w[2] = (__bf16)(m4[2] + e4[2] * __expf(0.5f * l4[2]));
        w[3] = (__bf16)(m4[3] + e4[3] * __expf(0.5f * l4[3]));
        *(bf16x4*)(W + (size_t)i * 4) = w;
    }
}

// ============================ Pass 1b: x -> bf16 ============================
__global__ void cvt_x_kernel(const float* __restrict__ x, __bf16* __restrict__ xb)
{
    const int n4 = B_ * L_ * I_ / 4;          // 4194304
    const int stride = gridDim.x * blockDim.x;
    for (int i = blockIdx.x * blockDim.x + threadIdx.x; i < n4; i += stride) {
        const f32x4 v = *(const f32x4*)(x + (size_t)i * 4);
        bf16x4 w;
        w[0] = (__bf16)v[0]; w[1] = (__bf16)v[1];
        w[2] = (__bf16)v[2]; w[3] = (__bf16)v[3];
        *(bf16x4*)(xb + (size_t)i * 4) = w;
    }
}

// ============================ Pass 2: bf16 GEMM (m97 structure) ============================
// C[b](512x1024) = Xb(512x1024,bf16) * W[b]^T(1024x1024,bf16) + bias, f32 out.
// 128x128 tile, BK=32, 4 waves (2x2, each 64x64 = 4x4 frags of 16x16x32).
__global__ __launch_bounds__(256) void bayes_gemm2(const __bf16* __restrict__ xb,
                                                   const __bf16* __restrict__ W,
                                                   const float* __restrict__ bias,
                                                   float* __restrict__ out)
{
    __shared__ __bf16 As[128 * 32];   // linear [row][k] — required by global_load_lds
    __shared__ __bf16 Bs[128 * 32];

    // bijective XCD swizzle: 1024 blocks -> 128 consecutive (batch-major) per XCD
    int bid = ((int)blockIdx.x & 7) * 128 + ((int)blockIdx.x >> 3);
    const int b  = bid >> 5;          // batch-major: blocks of one batch contiguous
    const int mt = (bid >> 3) & 3;    // 4 M-tiles
    const int nt = bid & 7;           // 8 N-tiles

    const int t    = threadIdx.x;     // 0..255  (== chunk id for staging)
    const int wave = t >> 6;
    const int lane = t & 63;
    const int wr   = wave >> 1;
    const int wc   = wave & 1;
    const int hr   = lane & 15;
    const int kq   = lane >> 4;

    const __bf16* xrow = xb + (size_t)b * L_ * I_ + (size_t)(mt * 128) * I_;
    const __bf16* wrow = W  + (size_t)b * O_ * I_ + (size_t)(nt * 128) * I_;

    f32x4 acc[4][4];
    #pragma unroll
    for (int m = 0; m < 4; ++m)
        #pragma unroll
        for (int n = 0; n < 4; ++n)
            acc[m][n] = (f32x4)(0.0f);

    // staging geometry: chunk c covers row c>>2, cols (c&3)*8 .. +8 (16B)
    const int c1 = t, c2 = t + 256;
    const int r1 = c1 >> 2, q1 = c1 & 3;
    const int r2 = c2 >> 2, q2 = c2 & 3;

    for (int k0 = 0; k0 < I_; k0 += 32) {
        gload_lds16(xrow + (size_t)r1 * I_ + k0 + q1 * 8, &As[c1 * 8]);
        gload_lds16(wrow + (size_t)r1 * I_ + k0 + q1 * 8, &Bs[c1 * 8]);
        gload_lds16(xrow + (size_t)r2 * I_ + k0 + q2 * 8, &As[c2 * 8]);
        gload_lds16(wrow + (size_t)r2 * I_ + k0 + q2 * 8, &Bs[c2 * 8]);
        __syncthreads();   // drains vmcnt before LDS reads

        bf16x8 af[4], bfr[4];
        #pragma unroll
        for (int m = 0; m < 4; ++m)
            af[m] = *(const bf16x8*)&As[(wr * 64 + m * 16 + hr) * 32 + kq * 8];
        #pragma unroll
        for (int n = 0; n < 4; ++n)
            bfr[n] = *(const bf16x8*)&Bs[(wc * 64 + n * 16 + hr) * 32 + kq * 8];
        #pragma unroll
        for (int m = 0; m < 4; ++m)
            #pragma unroll
            for (int n = 0; n < 4; ++n)
                acc[m][n] = __builtin_amdgcn_mfma_f32_16x16x32_bf16(af[m], bfr[n], acc[m][n], 0, 0, 0);

        __syncthreads();
    }

    // epilogue: C/D layout col=lane&15, row=(lane>>4)*4+reg (verified R1)
    float* ob = out + (size_t)b * L_ * O_;
    #pragma unroll
    for (int n = 0; n < 4; ++n) {
        const int col = nt * 128 + wc * 64 + n * 16 + hr;
        const float bv = bias[col];
        #pragma unroll
        for (int m = 0; m < 4; ++m) {
            const int row0 = mt * 128 + wr * 64 + m * 16 + kq * 4;
            #pragma unroll
            for (int j = 0; j < 4; ++j)
                ob[(size_t)(row0 + j) * O_ + col] = acc[m][n][j] + bv;
        }
    }
}

// ============================ Fallback: R1 fused kernel ============================
#define BMf 128
#define BNf 128
#define LDSPAD 40

__global__ void bayes_gemm_fused(const float* __restrict__ x,
                                 const float* __restrict__ wmean,
                                 const float* __restrict__ wlogvar,
                                 const float* __restrict__ bias,
                                 const float* __restrict__ noise,
                                 float* __restrict__ out)
{
    __shared__ __bf16 As[BMf * LDSPAD];
    __shared__ __bf16 Bs[BNf * LDSPAD];

    const int bid  = blockIdx.x;
    const int b    = bid >> 5;
    const int rem  = bid & 31;
    const int mt   = rem >> 3;
    const int nt   = rem & 7;
    const int brow = mt * BMf;
    const int bcol = nt * BNf;

    const int t    = threadIdx.x;
    const int wave = t >> 6;
    const int lane = t & 63;
    const int wr   = wave >> 1;
    const int wc   = wave & 1;
    const int hr   = lane & 15;
    const int kq   = lane >> 4;

    const float* xb = x     + (size_t)b * L_ * I_;
    const float* nb = noise + (size_t)b * O_ * I_;

    f32x4 acc[4][4];
    #pragma unroll
    for (int m = 0; m < 4; ++m)
        #pragma unroll
        for (int n = 0; n < 4; ++n)
            acc[m][n] = (f32x4)(0.0f);

    for (int k0 = 0; k0 < I_; k0 += 32) {
        #pragma unroll
        for (int j = 0; j < 4; ++j) {
            const int s   = t + j * 256;
            const int row = s >> 3;
            const int q   = s & 7;
            const float4 v = *(const float4*)(xb + (size_t)(brow + row) * I_ + k0 + q * 4);
            __bf16* dst = &As[row * LDSPAD + q * 4];
            dst[0] = (__bf16)v.x; dst[1] = (__bf16)v.y;
            dst[2] = (__bf16)v.z; dst[3] = (__bf16)v.w;
        }
        #pragma unroll
        for (int j = 0; j < 4; ++j) {
            const int s   = t + j * 256;
            const int row = s >> 3;
            const int q   = s & 7;
            const size_t off = (size_t)(bcol + row) * I_ + k0 + q * 4;
            const float4 m4 = *(const float4*)(wmean   + off);
            const float4 l4 = *(const float4*)(wlogvar + off);
            const float4 n4 = *(const float4*)(nb      + off);
            __bf16* dst = &Bs[row * LDSPAD + q * 4];
            dst[0] = (__bf16)(m4.x + n4.x * __expf(0.5f * l4.x));
            dst[1] = (__bf16)(m4.y + n4.y * __expf(0.5f * l4.y));
            dst[2] = (__bf16)(m4.z + n4.z * __expf(0.5f * l4.z));
            dst[3] = (__bf16)(m4.w + n4.w * __expf(0.5f * l4.w));
        }
        __syncthreads();

        bf16x8 af[4], bfr[4];
        #pragma unroll
        for (int m = 0; m < 4; ++m)
            af[m] = *(const bf16x8*)&As[(wr * 64 + m * 16 + hr) * LDSPAD + kq * 8];
        #pragma unroll
        for (int n = 0; n < 4; ++n)
            bfr[n] = *(const bf16x8*)&Bs[(wc * 64 + n * 16 + hr) * LDSPAD + kq * 8];
        #pragma unroll
        for (int m = 0; m < 4; ++m)
            #pragma unroll
            for (int n = 0; n < 4; ++n)
                acc[m][n] = __builtin_amdgcn_mfma_f32_16x16x32_bf16(af[m], bfr[n], acc[m][n], 0, 0, 0);

        __syncthreads();
    }

    float* ob = out + (size_t)b * L_ * O_;
    #pragma unroll
    for (int n = 0; n < 4; ++n) {
        const int col = bcol + wc * 64 + n * 16 + hr;
        const float bv = bias[col];
        #pragma unroll
        for (int m = 0; m < 4; ++m) {
            const int row0 = brow + wr * 64 + m * 16 + kq * 4;
            #pragma unroll
            for (int j = 0; j < 4; ++j)
                ob[(size_t)(row0 + j) * O_ + col] = acc[m][n][j] + bv;
        }
    }
}

extern "C" void kernel_launch(void* const* d_in, const int* in_sizes, int n_in,
                              void* d_out, int out_size, void* d_ws, size_t ws_size,
                              hipStream_t stream) {
    const float* x       = (const float*)d_in[0];
    const float* wmean   = (const float*)d_in[1];
    const float* wlogvar = (const float*)d_in[2];
    const float* bias    = (const float*)d_in[3];
    const float* noise   = (const float*)d_in[4];
    float* out           = (float*)d_out;

    const size_t w_bytes  = (size_t)B_ * O_ * I_ * 2;   // 64 MiB bf16 W
    const size_t xb_bytes = (size_t)B_ * L_ * I_ * 2;   // 32 MiB bf16 x

    if (ws_size >= w_bytes + xb_bytes) {
        __bf16* W  = (__bf16*)d_ws;
        __bf16* xb = (__bf16*)((char*)d_ws + w_bytes);
        gen_w_kernel<<<dim3(2048), dim3(256), 0, stream>>>(wmean, wlogvar, noise, W);
        cvt_x_kernel<<<dim3(1024), dim3(256), 0, stream>>>(x, xb);
        bayes_gemm2<<<dim3(1024), dim3(256), 0, stream>>>(xb, W, bias, out);
    } else {
        bayes_gemm_fused<<<dim3(1024), dim3(256), 0, stream>>>(
            x, wmean, wlogvar, bias, noise, out);
    }
}